// Round 1
// baseline (2285.416 us; speedup 1.0000x reference)
//
#include <hip/hip_runtime.h>

#define BLK 256

template<int NATOMS, int NPERMS, int DOUT>
struct PermSet { int p[NPERMS][NATOMS]; };

// One block processes ROWS=32 interaction rows.
//  1) cooperative gather of node rows -> LDS  (xs[ROWS][NATOMS*128])
//  2) per perm: layer1 h = rep @ w1 + b1, register tile 4 rows x 4 cols/thread
//     hacc += relu(h)   (sum of relu over perms; layer2 is linear so it runs once)
//  3) layer2: y = hacc @ w2 + NPERMS*b2 -> out
template<int NATOMS, int NPERMS, int DOUT>
__global__ __launch_bounds__(BLK, 2) void term_kernel(
    const float* __restrict__ node,   // (N,128)
    const int*   __restrict__ idx,    // (nrows,NATOMS) or nullptr => identity
    const float* __restrict__ w1,     // (NATOMS*128, 128)
    const float* __restrict__ b1,     // (128)
    const float* __restrict__ w2,     // (128, DOUT)
    const float* __restrict__ b2,     // (DOUT)
    float*       __restrict__ out,    // (nrows, DOUT)
    int nrows,
    PermSet<NATOMS, NPERMS, DOUT> perms)
{
    constexpr int ROWS = 32;
    constexpr int K    = NATOMS * 128;
    constexpr int HSTR = 132;                       // padded stride for h in LDS
    constexpr int SH   = (ROWS * K > ROWS * HSTR) ? ROWS * K : ROWS * HSTR;
    __shared__ float xs[SH];

    const int t  = threadIdx.x;
    const int r0 = blockIdx.x * ROWS;

    // ---- 1) gather node rows into LDS (float4, coalesced) ----
    constexpr int NSEG = K / 4;                     // float4 segments per row
    for (int i = t; i < ROWS * NSEG; i += BLK) {
        const int r   = i / NSEG;
        const int seg = i - r * NSEG;
        const int a   = seg >> 5;                   // which atom slot (128f = 32 seg)
        int row = r0 + r;
        if (row >= nrows) row = nrows - 1;          // tail clamp (not stored)
        const int nrow = idx ? idx[row * NATOMS + a] : row;
        const float4 v = reinterpret_cast<const float4*>(node + (size_t)nrow * 128)[seg & 31];
        reinterpret_cast<float4*>(xs)[(size_t)r * NSEG + seg] = v;
    }
    __syncthreads();

    // thread tile: 4 cols (c0..c0+3) x 4 rows (ra..ra+3)
    const int c0 = (t & 31) * 4;
    const int ra = (t >> 5) * 4;

    float hacc[4][4] = {};
    for (int p = 0; p < NPERMS; ++p) {
        float acc[4][4];
        const float4 bv = *reinterpret_cast<const float4*>(b1 + c0);
        #pragma unroll
        for (int i = 0; i < 4; ++i) {
            acc[i][0] = bv.x; acc[i][1] = bv.y; acc[i][2] = bv.z; acc[i][3] = bv.w;
        }

        #pragma unroll
        for (int a = 0; a < NATOMS; ++a) {
            const int xb = perms.p[p][a] * 128;     // which gathered slot feeds w1 slot a
            const float* wp = w1 + ((size_t)a * 128) * 128 + c0;
            #pragma unroll 4
            for (int kk = 0; kk < 128; kk += 2) {
                const float4 wv0 = *reinterpret_cast<const float4*>(wp + (size_t)kk * 128);
                const float4 wv1 = *reinterpret_cast<const float4*>(wp + (size_t)(kk + 1) * 128);
                #pragma unroll
                for (int i = 0; i < 4; ++i) {
                    const float2 x2 = *reinterpret_cast<const float2*>(&xs[(size_t)(ra + i) * K + xb + kk]);
                    acc[i][0] += x2.x * wv0.x; acc[i][1] += x2.x * wv0.y;
                    acc[i][2] += x2.x * wv0.z; acc[i][3] += x2.x * wv0.w;
                    acc[i][0] += x2.y * wv1.x; acc[i][1] += x2.y * wv1.y;
                    acc[i][2] += x2.y * wv1.z; acc[i][3] += x2.y * wv1.w;
                }
            }
        }
        #pragma unroll
        for (int i = 0; i < 4; ++i)
            #pragma unroll
            for (int j = 0; j < 4; ++j)
                hacc[i][j] += fmaxf(acc[i][j], 0.0f);
    }

    __syncthreads();                                // everyone done reading xs
    // ---- write accumulated relu(h) to LDS (aliased over xs) ----
    #pragma unroll
    for (int i = 0; i < 4; ++i)
        #pragma unroll
        for (int j = 0; j < 4; ++j)
            xs[(size_t)(ra + i) * HSTR + c0 + j] = hacc[i][j];
    __syncthreads();

    // ---- 3) layer 2 ----
    if (t < ROWS * DOUT) {
        const int r = t / DOUT;
        const int o = t - r * DOUT;
        float y = b2[o] * (float)NPERMS;
        #pragma unroll 8
        for (int c = 0; c < 128; ++c)
            y += xs[(size_t)r * HSTR + c] * w2[(size_t)c * DOUT + o];
        const int row = r0 + r;
        if (row < nrows) out[(size_t)row * DOUT + o] = y;
    }
}

extern "C" void kernel_launch(void* const* d_in, const int* in_sizes, int n_in,
                              void* d_out, int out_size, void* d_ws, size_t ws_size,
                              hipStream_t stream) {
    const float* node = (const float*)d_in[0];
    const int* bidx = (const int*)d_in[1];
    const int* gidx = (const int*)d_in[2];
    const int* pidx = (const int*)d_in[3];
    const int* iidx = (const int*)d_in[4];

    const float* aw1 = (const float*)d_in[5];
    const float* ab1 = (const float*)d_in[6];
    const float* aw2 = (const float*)d_in[7];
    const float* ab2 = (const float*)d_in[8];
    const float* bw1 = (const float*)d_in[9];
    const float* bb1 = (const float*)d_in[10];
    const float* bw2 = (const float*)d_in[11];
    const float* bb2 = (const float*)d_in[12];
    const float* gw1 = (const float*)d_in[13];
    const float* gb1 = (const float*)d_in[14];
    const float* gw2 = (const float*)d_in[15];
    const float* gb2 = (const float*)d_in[16];
    const float* pw1 = (const float*)d_in[17];
    const float* pb1 = (const float*)d_in[18];
    const float* pw2 = (const float*)d_in[19];
    const float* pb2 = (const float*)d_in[20];
    const float* iw1 = (const float*)d_in[21];
    const float* ib1 = (const float*)d_in[22];
    const float* iw2 = (const float*)d_in[23];
    const float* ib2 = (const float*)d_in[24];

    const int N  = in_sizes[0] / 128;
    const int NB = in_sizes[1] / 2;
    const int NA = in_sizes[2] / 3;
    const int NP = in_sizes[3] / 4;
    const int NI = in_sizes[4] / 4;

    float* out   = (float*)d_out;
    float* out_a = out;
    float* out_b = out_a + (size_t)N  * 2;
    float* out_g = out_b + (size_t)NB * 2;
    float* out_p = out_g + (size_t)NA * 2;
    float* out_i = out_p + (size_t)NP * 6;

    PermSet<1, 1, 2> pa{{{0}}};
    PermSet<2, 2, 2> pb{{{0, 1}, {1, 0}}};
    PermSet<3, 2, 2> pg{{{0, 1, 2}, {2, 1, 0}}};
    PermSet<4, 2, 6> pp{{{0, 1, 2, 3}, {3, 2, 1, 0}}};
    PermSet<4, 3, 6> pi{{{0, 1, 2, 3}, {2, 1, 3, 0}, {3, 1, 0, 2}}};

    constexpr int ROWS = 32;
    term_kernel<1, 1, 2><<<(N  + ROWS - 1) / ROWS, BLK, 0, stream>>>(node, nullptr, aw1, ab1, aw2, ab2, out_a, N,  pa);
    term_kernel<2, 2, 2><<<(NB + ROWS - 1) / ROWS, BLK, 0, stream>>>(node, bidx,    bw1, bb1, bw2, bb2, out_b, NB, pb);
    term_kernel<3, 2, 2><<<(NA + ROWS - 1) / ROWS, BLK, 0, stream>>>(node, gidx,    gw1, gb1, gw2, gb2, out_g, NA, pg);
    term_kernel<4, 2, 6><<<(NP + ROWS - 1) / ROWS, BLK, 0, stream>>>(node, pidx,    pw1, pb1, pw2, pb2, out_p, NP, pp);
    term_kernel<4, 3, 6><<<(NI + ROWS - 1) / ROWS, BLK, 0, stream>>>(node, iidx,    iw1, ib1, iw2, ib2, out_i, NI, pi);
}

// Round 2
// 495.242 us; speedup vs baseline: 4.6147x; 4.6147x over previous
//
#include <hip/hip_runtime.h>

#define BLK 256

typedef __attribute__((ext_vector_type(8))) short bf16x8;
typedef __attribute__((ext_vector_type(4))) float f32x4;

struct IPerm { int v[12]; };   // up to 3 perms x 4 atoms (inverse perms)

__device__ __forceinline__ unsigned short f2bf(float x) {
    unsigned int u = __builtin_bit_cast(unsigned int, x);
    u += 0x7fffu + ((u >> 16) & 1u);
    return (unsigned short)(u >> 16);
}

// ---- pre-pass 1: node_reps fp32 -> bf16 ----
__global__ void conv_node(const float* __restrict__ x, unsigned short* __restrict__ o, int n4) {
    int tid = blockIdx.x * BLK + threadIdx.x;
    if (tid >= n4) return;
    const float4 v = reinterpret_cast<const float4*>(x)[tid];
    ushort4 r;
    r.x = f2bf(v.x); r.y = f2bf(v.y); r.z = f2bf(v.z); r.w = f2bf(v.w);
    reinterpret_cast<ushort4*>(o)[tid] = r;
}

// ---- pre-pass 2: pack w1 (K x 128 fp32) into per-perm B-fragment layout ----
// element order: (((ct*KT + kt)*64 + lane)*8 + j), lane supplies col = ct*16+(l&15),
// k = kt*32 + (l>>4)*8 + j; source row permuted per inverse perm on 128-blocks.
template<int K>
__global__ void pack_w1(const float* __restrict__ w1, unsigned short* __restrict__ o,
                        int nperms, IPerm ip) {
    constexpr int KT = K / 32;
    const int per = K * 128;
    int tid = blockIdx.x * BLK + threadIdx.x;
    if (tid >= nperms * per) return;
    const int p = tid / per;
    const int e = tid - p * per;
    const int j = e & 7;
    const int l = (e >> 3) & 63;
    const int ctkt = e >> 9;
    const int kt = ctkt % KT;
    const int ct = ctkt / KT;
    const int col = ct * 16 + (l & 15);
    const int k = kt * 32 + (l >> 4) * 8 + j;
    const int srow = ip.v[p * 4 + (k >> 7)] * 128 + (k & 127);
    o[tid] = f2bf(w1[(size_t)srow * 128 + col]);
}

// ---- main term kernel: 64 rows/block, 4 waves, MFMA 16x16x32 bf16 ----
template<int NATOMS, int NPERMS, int DOUT>
__global__ __launch_bounds__(BLK) void term_mfma(
    const unsigned short* __restrict__ nodeb,  // (N,128) bf16
    const int* __restrict__ idx,               // (nrows,NATOMS) or nullptr
    const unsigned short* __restrict__ pack,   // NPERMS * K * 128 bf16 packed
    const float* __restrict__ b1,              // (128)
    const float* __restrict__ w2,              // (128,DOUT)
    const float* __restrict__ b2,              // (DOUT)
    float* __restrict__ out,                   // (nrows,DOUT)
    int nrows)
{
    constexpr int ROWS = 64;
    constexpr int K    = NATOMS * 128;
    constexpr int K2   = K * 2;        // LDS row stride bytes
    constexpr int KT   = K / 32;
    constexpr int CH   = K / 8;        // 16B chunks per row
    constexpr int XB   = ROWS * K2;
    constexpr int HB   = ROWS * 132 * 4;
    constexpr int SHB  = XB > HB ? XB : HB;
    __shared__ __align__(16) unsigned char lds[SHB];

    const int t  = threadIdx.x;
    const int l  = t & 63;
    const int w  = t >> 6;
    const int hi = l >> 4;
    const int r0 = blockIdx.x * ROWS;

    // ---- gather bf16 node rows -> LDS (XOR-swizzled rows) ----
    for (int i = t; i < ROWS * CH; i += BLK) {
        const int r = i / CH;
        const int c = i - r * CH;
        int row = r0 + r; if (row >= nrows) row = nrows - 1;
        const int a = c >> 4;
        const int nrow = idx ? idx[row * NATOMS + a] : row;
        const uint4 v = *reinterpret_cast<const uint4*>(nodeb + (size_t)nrow * 128 + (c & 15) * 8);
        *reinterpret_cast<uint4*>(lds + r * K2 + ((c * 16) ^ ((r & 7) << 4))) = v;
    }
    __syncthreads();

    // wave w owns col tiles {2w, 2w+1}, all 4 row tiles
    const int ct0  = w * 2;
    const int col0 = ct0 * 16 + (l & 15);
    const int col1 = col0 + 16;

    float hacc[4][2][4] = {};

    for (int p = 0; p < NPERMS; ++p) {
        f32x4 acc[4][2];
        const float bv0 = b1[col0];
        const float bv1 = b1[col1];
        #pragma unroll
        for (int rt = 0; rt < 4; ++rt) {
            acc[rt][0] = (f32x4){bv0, bv0, bv0, bv0};
            acc[rt][1] = (f32x4){bv1, bv1, bv1, bv1};
        }
        const unsigned short* pb = pack + (size_t)p * K * 128;

        #pragma unroll 4
        for (int kt = 0; kt < KT; ++kt) {
            bf16x8 a[4];
            #pragma unroll
            for (int rt = 0; rt < 4; ++rt) {
                const int row = rt * 16 + (l & 15);
                const int off = (kt * 64 + hi * 16) ^ ((row & 7) << 4);
                a[rt] = *reinterpret_cast<const bf16x8*>(lds + row * K2 + off);
            }
            const bf16x8 bA = *reinterpret_cast<const bf16x8*>(pb + ((size_t)(ct0 * KT + kt) * 64 + l) * 8);
            const bf16x8 bB = *reinterpret_cast<const bf16x8*>(pb + ((size_t)((ct0 + 1) * KT + kt) * 64 + l) * 8);
            #pragma unroll
            for (int rt = 0; rt < 4; ++rt) {
                acc[rt][0] = __builtin_amdgcn_mfma_f32_16x16x32_bf16(a[rt], bA, acc[rt][0], 0, 0, 0);
                acc[rt][1] = __builtin_amdgcn_mfma_f32_16x16x32_bf16(a[rt], bB, acc[rt][1], 0, 0, 0);
            }
        }
        #pragma unroll
        for (int rt = 0; rt < 4; ++rt)
            #pragma unroll
            for (int c = 0; c < 2; ++c)
                #pragma unroll
                for (int i = 0; i < 4; ++i)
                    hacc[rt][c][i] += fmaxf(acc[rt][c][i], 0.0f);
    }

    __syncthreads();   // done reading X tile; reuse LDS for h staging
    float* hs = reinterpret_cast<float*>(lds);
    #pragma unroll
    for (int rt = 0; rt < 4; ++rt) {
        const int rbase = rt * 16 + hi * 4;
        #pragma unroll
        for (int i = 0; i < 4; ++i) {
            hs[(size_t)(rbase + i) * 132 + col0] = hacc[rt][0][i];
            hs[(size_t)(rbase + i) * 132 + col1] = hacc[rt][1][i];
        }
    }
    __syncthreads();

    // ---- layer 2 ----
    for (int q = t; q < ROWS * DOUT; q += BLK) {
        const int r = q / DOUT;
        const int o = q - r * DOUT;
        float y = b2[o] * (float)NPERMS;
        #pragma unroll 8
        for (int c = 0; c < 128; ++c)
            y += hs[(size_t)r * 132 + c] * w2[(size_t)c * DOUT + o];
        const int row = r0 + r;
        if (row < nrows) out[(size_t)row * DOUT + o] = y;
    }
}

extern "C" void kernel_launch(void* const* d_in, const int* in_sizes, int n_in,
                              void* d_out, int out_size, void* d_ws, size_t ws_size,
                              hipStream_t stream) {
    const float* node = (const float*)d_in[0];
    const int* bidx = (const int*)d_in[1];
    const int* gidx = (const int*)d_in[2];
    const int* pidx = (const int*)d_in[3];
    const int* iidx = (const int*)d_in[4];

    const float* aw1 = (const float*)d_in[5];
    const float* ab1 = (const float*)d_in[6];
    const float* aw2 = (const float*)d_in[7];
    const float* ab2 = (const float*)d_in[8];
    const float* bw1 = (const float*)d_in[9];
    const float* bb1 = (const float*)d_in[10];
    const float* bw2 = (const float*)d_in[11];
    const float* bb2 = (const float*)d_in[12];
    const float* gw1 = (const float*)d_in[13];
    const float* gb1 = (const float*)d_in[14];
    const float* gw2 = (const float*)d_in[15];
    const float* gb2 = (const float*)d_in[16];
    const float* pw1 = (const float*)d_in[17];
    const float* pb1 = (const float*)d_in[18];
    const float* pw2 = (const float*)d_in[19];
    const float* pb2 = (const float*)d_in[20];
    const float* iw1 = (const float*)d_in[21];
    const float* ib1 = (const float*)d_in[22];
    const float* iw2 = (const float*)d_in[23];
    const float* ib2 = (const float*)d_in[24];

    const int N  = in_sizes[0] / 128;
    const int NB = in_sizes[1] / 2;
    const int NA = in_sizes[2] / 3;
    const int NP = in_sizes[3] / 4;
    const int NI = in_sizes[4] / 4;

    float* out   = (float*)d_out;
    float* out_a = out;
    float* out_b = out_a + (size_t)N  * 2;
    float* out_g = out_b + (size_t)NB * 2;
    float* out_p = out_g + (size_t)NA * 2;
    float* out_i = out_p + (size_t)NP * 6;

    // ---- workspace layout (bf16 elements) ----
    unsigned short* nodeb = (unsigned short*)d_ws;
    size_t off = (size_t)N * 128;
    unsigned short* packA = nodeb + off; off += (size_t)1 * 128 * 128;
    unsigned short* packB = nodeb + off; off += (size_t)2 * 256 * 128;
    unsigned short* packG = nodeb + off; off += (size_t)2 * 384 * 128;
    unsigned short* packP = nodeb + off; off += (size_t)2 * 512 * 128;
    unsigned short* packI = nodeb + off; off += (size_t)3 * 512 * 128;

    // ---- pre-pass: convert node, pack weights ----
    {
        const int n4 = N * 128 / 4;
        conv_node<<<(n4 + BLK - 1) / BLK, BLK, 0, stream>>>(node, nodeb, n4);
    }
    // inverse perms
    IPerm ipa{{0,0,0,0,  0,0,0,0,  0,0,0,0}};
    IPerm ipb{{0,1,0,0,  1,0,0,0,  0,0,0,0}};
    IPerm ipg{{0,1,2,0,  2,1,0,0,  0,0,0,0}};
    IPerm ipp{{0,1,2,3,  3,2,1,0,  0,0,0,0}};
    IPerm ipi{{0,1,2,3,  3,1,0,2,  2,1,3,0}};   // inverses of (0123),(2130),(3102)

    pack_w1<128><<<(1 * 128 * 128 + BLK - 1) / BLK, BLK, 0, stream>>>(aw1, packA, 1, ipa);
    pack_w1<256><<<(2 * 256 * 128 + BLK - 1) / BLK, BLK, 0, stream>>>(bw1, packB, 2, ipb);
    pack_w1<384><<<(2 * 384 * 128 + BLK - 1) / BLK, BLK, 0, stream>>>(gw1, packG, 2, ipg);
    pack_w1<512><<<(2 * 512 * 128 + BLK - 1) / BLK, BLK, 0, stream>>>(pw1, packP, 2, ipp);
    pack_w1<512><<<(3 * 512 * 128 + BLK - 1) / BLK, BLK, 0, stream>>>(iw1, packI, 3, ipi);

    // ---- term kernels ----
    constexpr int ROWS = 64;
    term_mfma<1, 1, 2><<<(N  + ROWS - 1) / ROWS, BLK, 0, stream>>>(nodeb, nullptr, packA, ab1, aw2, ab2, out_a, N);
    term_mfma<2, 2, 2><<<(NB + ROWS - 1) / ROWS, BLK, 0, stream>>>(nodeb, bidx,    packB, bb1, bw2, bb2, out_b, NB);
    term_mfma<3, 2, 2><<<(NA + ROWS - 1) / ROWS, BLK, 0, stream>>>(nodeb, gidx,    packG, gb1, gw2, gb2, out_g, NA);
    term_mfma<4, 2, 6><<<(NP + ROWS - 1) / ROWS, BLK, 0, stream>>>(nodeb, pidx,    packP, pb1, pw2, pb2, out_p, NP);
    term_mfma<4, 3, 6><<<(NI + ROWS - 1) / ROWS, BLK, 0, stream>>>(nodeb, iidx,    packI, ib1, iw2, ib2, out_i, NI);
}

// Round 3
// 390.387 us; speedup vs baseline: 5.8542x; 1.2686x over previous
//
#include <hip/hip_runtime.h>

#define PBLK 256

typedef __attribute__((ext_vector_type(8))) short bf16x8;
typedef __attribute__((ext_vector_type(4))) float f32x4;

struct IPerm { int v[12]; };   // up to 3 perms x 4 atoms (inverse perms)

__device__ __forceinline__ unsigned short f2bf(float x) {
    unsigned int u = __builtin_bit_cast(unsigned int, x);
    u += 0x7fffu + ((u >> 16) & 1u);
    return (unsigned short)(u >> 16);
}

// ---- pre-pass 1: node_reps fp32 -> bf16 ----
__global__ void conv_node(const float* __restrict__ x, unsigned short* __restrict__ o, int n4) {
    int tid = blockIdx.x * PBLK + threadIdx.x;
    if (tid >= n4) return;
    const float4 v = reinterpret_cast<const float4*>(x)[tid];
    ushort4 r;
    r.x = f2bf(v.x); r.y = f2bf(v.y); r.z = f2bf(v.z); r.w = f2bf(v.w);
    reinterpret_cast<ushort4*>(o)[tid] = r;
}

// ---- pre-pass 2: pack w1 (K x 128 fp32) into per-perm B-fragment layout ----
// element order: (((ct*KT + kt)*64 + lane)*8 + j); lane -> col = ct*16+(l&15),
// k = kt*32 + (l>>4)*8 + j; source row permuted per inverse perm on 128-blocks.
template<int K>
__global__ void pack_w1(const float* __restrict__ w1, unsigned short* __restrict__ o,
                        int nperms, IPerm ip) {
    constexpr int KT = K / 32;
    const int per = K * 128;
    int tid = blockIdx.x * PBLK + threadIdx.x;
    if (tid >= nperms * per) return;
    const int p = tid / per;
    const int e = tid - p * per;
    const int j = e & 7;
    const int l = (e >> 3) & 63;
    const int ctkt = e >> 9;
    const int kt = ctkt % KT;
    const int ct = ctkt / KT;
    const int col = ct * 16 + (l & 15);
    const int k = kt * 32 + (l >> 4) * 8 + j;
    const int srow = ip.v[p * 4 + (k >> 7)] * 128 + (k & 127);
    o[tid] = f2bf(w1[(size_t)srow * 128 + col]);
}

// ---- main term kernel ----
// 64 rows/block, 512 threads (8 waves), wave w owns col-tile w (cols 16w..16w+15).
// X staged per-atom (16KB buffers, double-buffered); async-stage split:
// issue atom a+1 loads -> compute atom a MFMAs -> barrier -> ds_write -> barrier.
// All NPERMS accumulators live in registers (perms folded into packed W1).
template<int NATOMS, int NPERMS, int DOUT, int MINW>
__global__ __launch_bounds__(512, MINW) void term_mfma(
    const unsigned short* __restrict__ nodeb,  // (N,128) bf16
    const int* __restrict__ idx,               // (nrows,NATOMS) or nullptr
    const unsigned short* __restrict__ pack,   // NPERMS * K * 128 bf16 packed
    const float* __restrict__ b1,              // (128)
    const float* __restrict__ w2,              // (128,DOUT)
    const float* __restrict__ b2,              // (DOUT)
    float* __restrict__ out,                   // (nrows,DOUT)
    int nrows)
{
    constexpr int ROWS = 64;
    constexpr int KT   = NATOMS * 4;           // total k-tiles (K/32)
    __shared__ __align__(16) unsigned char lds[32768];   // 2 x 16KB atom bufs / 32KB h

    const int t  = threadIdx.x;
    const int l  = t & 63;
    const int w  = t >> 6;                     // wave id = col tile
    const int hi = l >> 4;
    const int lm = l & 15;
    const int r0 = blockIdx.x * ROWS;

    const int col = w * 16 + lm;
    const float bv = b1[col];
    f32x4 acc[NPERMS][4];
    #pragma unroll
    for (int p = 0; p < NPERMS; ++p)
        #pragma unroll
        for (int rt = 0; rt < 4; ++rt)
            acc[p][rt] = (f32x4){bv, bv, bv, bv};

    // ---- prologue: stage atom 0 into buf0 ----
    {
        uint4 pre[2];
        #pragma unroll
        for (int it = 0; it < 2; ++it) {
            const int i = t + it * 512;
            const int r = i >> 4, c = i & 15;
            int row = r0 + r; if (row >= nrows) row = nrows - 1;
            const int nrow = idx ? idx[row * NATOMS] : row;
            pre[it] = *reinterpret_cast<const uint4*>(nodeb + (size_t)nrow * 128 + c * 8);
        }
        #pragma unroll
        for (int it = 0; it < 2; ++it) {
            const int i = t + it * 512;
            const int r = i >> 4, c = i & 15;
            *reinterpret_cast<uint4*>(lds + r * 256 + ((c * 16) ^ ((r & 7) << 4))) = pre[it];
        }
    }
    __syncthreads();

    #pragma unroll
    for (int a = 0; a < NATOMS; ++a) {
        // (1) issue atom a+1 global loads (overlap with compute below)
        uint4 pre[2];
        const bool have = (a + 1 < NATOMS);
        if (have) {
            #pragma unroll
            for (int it = 0; it < 2; ++it) {
                const int i = t + it * 512;
                const int r = i >> 4, c = i & 15;
                int row = r0 + r; if (row >= nrows) row = nrows - 1;
                const int nrow = idx ? idx[row * NATOMS + a + 1] : row;
                pre[it] = *reinterpret_cast<const uint4*>(nodeb + (size_t)nrow * 128 + c * 8);
            }
        }
        // (2) compute atom a from buf[a&1]
        const unsigned char* xb = lds + (a & 1) * 16384;
        #pragma unroll
        for (int ktl = 0; ktl < 4; ++ktl) {
            const int kt = a * 4 + ktl;
            bf16x8 av[4];
            #pragma unroll
            for (int rt = 0; rt < 4; ++rt) {
                const int row = rt * 16 + lm;
                av[rt] = *reinterpret_cast<const bf16x8*>(
                    xb + row * 256 + ((ktl * 64 + hi * 16) ^ ((row & 7) << 4)));
            }
            #pragma unroll
            for (int p = 0; p < NPERMS; ++p) {
                const bf16x8 bvv = *reinterpret_cast<const bf16x8*>(
                    pack + (size_t)p * KT * 32 * 128 + ((size_t)(w * KT + kt) * 64 + l) * 8);
                #pragma unroll
                for (int rt = 0; rt < 4; ++rt)
                    acc[p][rt] = __builtin_amdgcn_mfma_f32_16x16x32_bf16(av[rt], bvv, acc[p][rt], 0, 0, 0);
            }
        }
        __syncthreads();                       // all waves done reading buf[(a+1)&1] (from a-1)
        // (3) write prefetched atom a+1 (vmcnt drained here, hidden under compute)
        if (have) {
            #pragma unroll
            for (int it = 0; it < 2; ++it) {
                const int i = t + it * 512;
                const int r = i >> 4, c = i & 15;
                *reinterpret_cast<uint4*>(
                    lds + ((a + 1) & 1) * 16384 + r * 256 + ((c * 16) ^ ((r & 7) << 4))) = pre[it];
            }
        }
        __syncthreads();
    }

    // ---- stage h = sum_p relu(acc_p) into LDS (fp32, swizzled) ----
    float* hs = reinterpret_cast<float*>(lds);
    #pragma unroll
    for (int rt = 0; rt < 4; ++rt) {
        #pragma unroll
        for (int i = 0; i < 4; ++i) {
            const int row = rt * 16 + hi * 4 + i;
            float v = 0.0f;
            #pragma unroll
            for (int p = 0; p < NPERMS; ++p) v += fmaxf(acc[p][rt][i], 0.0f);
            hs[row * 128 + (col ^ ((row & 7) << 2))] = v;
        }
    }
    __syncthreads();

    // ---- layer 2: y = h @ w2 + NPERMS*b2 ----
    if (t < ROWS * DOUT) {
        const int r = t / DOUT;
        const int o = t - r * DOUT;
        float y0 = 0.f, y1 = 0.f, y2 = 0.f, y3 = 0.f;
        #pragma unroll 4
        for (int c = 0; c < 128; c += 4) {
            y0 += hs[r * 128 + ((c    ) ^ ((r & 7) << 2))] * w2[(size_t)(c    ) * DOUT + o];
            y1 += hs[r * 128 + ((c + 1) ^ ((r & 7) << 2))] * w2[(size_t)(c + 1) * DOUT + o];
            y2 += hs[r * 128 + ((c + 2) ^ ((r & 7) << 2))] * w2[(size_t)(c + 2) * DOUT + o];
            y3 += hs[r * 128 + ((c + 3) ^ ((r & 7) << 2))] * w2[(size_t)(c + 3) * DOUT + o];
        }
        const float y = b2[o] * (float)NPERMS + ((y0 + y1) + (y2 + y3));
        const int row = r0 + r;
        if (row < nrows) out[(size_t)row * DOUT + o] = y;
    }
}

extern "C" void kernel_launch(void* const* d_in, const int* in_sizes, int n_in,
                              void* d_out, int out_size, void* d_ws, size_t ws_size,
                              hipStream_t stream) {
    const float* node = (const float*)d_in[0];
    const int* bidx = (const int*)d_in[1];
    const int* gidx = (const int*)d_in[2];
    const int* pidx = (const int*)d_in[3];
    const int* iidx = (const int*)d_in[4];

    const float* aw1 = (const float*)d_in[5];
    const float* ab1 = (const float*)d_in[6];
    const float* aw2 = (const float*)d_in[7];
    const float* ab2 = (const float*)d_in[8];
    const float* bw1 = (const float*)d_in[9];
    const float* bb1 = (const float*)d_in[10];
    const float* bw2 = (const float*)d_in[11];
    const float* bb2 = (const float*)d_in[12];
    const float* gw1 = (const float*)d_in[13];
    const float* gb1 = (const float*)d_in[14];
    const float* gw2 = (const float*)d_in[15];
    const float* gb2 = (const float*)d_in[16];
    const float* pw1 = (const float*)d_in[17];
    const float* pb1 = (const float*)d_in[18];
    const float* pw2 = (const float*)d_in[19];
    const float* pb2 = (const float*)d_in[20];
    const float* iw1 = (const float*)d_in[21];
    const float* ib1 = (const float*)d_in[22];
    const float* iw2 = (const float*)d_in[23];
    const float* ib2 = (const float*)d_in[24];

    const int N  = in_sizes[0] / 128;
    const int NB = in_sizes[1] / 2;
    const int NA = in_sizes[2] / 3;
    const int NP = in_sizes[3] / 4;
    const int NI = in_sizes[4] / 4;

    float* out   = (float*)d_out;
    float* out_a = out;
    float* out_b = out_a + (size_t)N  * 2;
    float* out_g = out_b + (size_t)NB * 2;
    float* out_p = out_g + (size_t)NA * 2;
    float* out_i = out_p + (size_t)NP * 6;

    // ---- workspace layout (bf16 elements) ----
    unsigned short* nodeb = (unsigned short*)d_ws;
    size_t off = (size_t)N * 128;
    unsigned short* packA = nodeb + off; off += (size_t)1 * 128 * 128;
    unsigned short* packB = nodeb + off; off += (size_t)2 * 256 * 128;
    unsigned short* packG = nodeb + off; off += (size_t)2 * 384 * 128;
    unsigned short* packP = nodeb + off; off += (size_t)2 * 512 * 128;
    unsigned short* packI = nodeb + off; off += (size_t)3 * 512 * 128;

    // ---- pre-pass: convert node, pack weights ----
    {
        const int n4 = N * 128 / 4;
        conv_node<<<(n4 + PBLK - 1) / PBLK, PBLK, 0, stream>>>(node, nodeb, n4);
    }
    IPerm ipa{{0,0,0,0,  0,0,0,0,  0,0,0,0}};
    IPerm ipb{{0,1,0,0,  1,0,0,0,  0,0,0,0}};
    IPerm ipg{{0,1,2,0,  2,1,0,0,  0,0,0,0}};
    IPerm ipp{{0,1,2,3,  3,2,1,0,  0,0,0,0}};
    IPerm ipi{{0,1,2,3,  3,1,0,2,  2,1,3,0}};   // inverses of (0123),(2130),(3102)

    pack_w1<128><<<(1 * 128 * 128 + PBLK - 1) / PBLK, PBLK, 0, stream>>>(aw1, packA, 1, ipa);
    pack_w1<256><<<(2 * 256 * 128 + PBLK - 1) / PBLK, PBLK, 0, stream>>>(bw1, packB, 2, ipb);
    pack_w1<384><<<(2 * 384 * 128 + PBLK - 1) / PBLK, PBLK, 0, stream>>>(gw1, packG, 2, ipg);
    pack_w1<512><<<(2 * 512 * 128 + PBLK - 1) / PBLK, PBLK, 0, stream>>>(pw1, packP, 2, ipp);
    pack_w1<512><<<(3 * 512 * 128 + PBLK - 1) / PBLK, PBLK, 0, stream>>>(iw1, packI, 3, ipi);

    // ---- term kernels ----
    constexpr int ROWS = 64;
    term_mfma<1, 1, 2, 4><<<(N  + ROWS - 1) / ROWS, 512, 0, stream>>>(nodeb, nullptr, packA, ab1, aw2, ab2, out_a, N);
    term_mfma<2, 2, 2, 4><<<(NB + ROWS - 1) / ROWS, 512, 0, stream>>>(nodeb, bidx,    packB, bb1, bw2, bb2, out_b, NB);
    term_mfma<3, 2, 2, 4><<<(NA + ROWS - 1) / ROWS, 512, 0, stream>>>(nodeb, gidx,    packG, gb1, gw2, gb2, out_g, NA);
    term_mfma<4, 2, 6, 4><<<(NP + ROWS - 1) / ROWS, 512, 0, stream>>>(nodeb, pidx,    packP, pb1, pw2, pb2, out_p, NP);
    term_mfma<4, 3, 6, 2><<<(NI + ROWS - 1) / ROWS, 512, 0, stream>>>(nodeb, iidx,    packI, ib1, iw2, ib2, out_i, NI);
}